// Round 1
// baseline (181.759 us; speedup 1.0000x reference)
//
#include <hip/hip_runtime.h>

#define N 8192
#define H 256
#define TOPK 16
#define NSEC 11
#define NEG_SLOPE 0.2
#define NB 256                 // K1 blocks (one per CU)
#define NT 256                 // threads per block
#define RPB (N / NB)           // 32 rows per block
#define NSL 8                  // slices per sector
#define SLICE (N / NSL)        // 1024 elements per slice
#define IDX_SENT 0x7fffffff

__device__ __forceinline__ bool better(double av, int ai, double bv, int bi) {
    return (av > bv) || (av == bv && ai < bi);
}

// ---------------------------------------------------------------------------
// K1: redundant v = W^T a per block (4 independent f64 chains, proven),
// then s1/s2 for the block's 32 rows. Unchanged numerics vs R11 best.
// NEW: block 0 zeroes the per-sector arrival counters for the fused K2.
// ---------------------------------------------------------------------------
__global__ __launch_bounds__(NT) void compute_v_s(
    const float* __restrict__ E, const float* __restrict__ W,
    const float* __restrict__ a,
    float* __restrict__ s1f, double* __restrict__ s2g,
    int* __restrict__ arrive)
{
    __shared__ float sa[2 * H];
    __shared__ double sv1[H];
    __shared__ double sv2[H];

    int t = threadIdx.x;
    int blk = blockIdx.x;
    int lane = t & 63;
    int w = t >> 6;  // wave 0..3

    if (blk == 0 && t < NSEC) arrive[t] = 0;   // visible to fused kernel at dispatch boundary

    sa[t] = a[t];
    sa[t + H] = a[t + H];
    __syncthreads();

    // ---- phase A: thread t owns column t; 4 independent chains ----
    {
        double a1_0 = 0.0, a1_1 = 0.0, a1_2 = 0.0, a1_3 = 0.0;
        double a2_0 = 0.0, a2_1 = 0.0, a2_2 = 0.0, a2_3 = 0.0;
        for (int j = 0; j < H; j += 4) {
            double w0 = (double)W[(j + 0) * H + t];
            double w1 = (double)W[(j + 1) * H + t];
            double w2 = (double)W[(j + 2) * H + t];
            double w3 = (double)W[(j + 3) * H + t];
            a1_0 += w0 * (double)sa[j + 0];
            a1_1 += w1 * (double)sa[j + 1];
            a1_2 += w2 * (double)sa[j + 2];
            a1_3 += w3 * (double)sa[j + 3];
            a2_0 += w0 * (double)sa[H + j + 0];
            a2_1 += w1 * (double)sa[H + j + 1];
            a2_2 += w2 * (double)sa[H + j + 2];
            a2_3 += w3 * (double)sa[H + j + 3];
        }
        sv1[t] = (a1_0 + a1_1) + (a1_2 + a1_3);
        sv2[t] = (a2_0 + a2_1) + (a2_2 + a2_3);
    }
    __syncthreads();

    // ---- phase B: rows [blk*32 .. +32), wave-per-row, loads batched ----
    {
        float4 e[RPB / 4];
#pragma unroll
        for (int q = 0; q < RPB / 4; ++q) {
            int row = blk * RPB + (w + 4 * q);
            e[q] = ((const float4*)(E + (size_t)row * H))[lane];
        }
        int base = lane * 4;
        double b10 = sv1[base + 0], b11 = sv1[base + 1],
               b12 = sv1[base + 2], b13 = sv1[base + 3];
        double b20 = sv2[base + 0], b21 = sv2[base + 1],
               b22 = sv2[base + 2], b23 = sv2[base + 3];
#pragma unroll
        for (int q = 0; q < RPB / 4; ++q) {
            int row = blk * RPB + (w + 4 * q);
            double acc1 = (double)e[q].x * b10 + (double)e[q].y * b11 +
                          (double)e[q].z * b12 + (double)e[q].w * b13;
            double acc2 = (double)e[q].x * b20 + (double)e[q].y * b21 +
                          (double)e[q].z * b22 + (double)e[q].w * b23;
            for (int o = 32; o > 0; o >>= 1) {
                acc1 += __shfl_down(acc1, o);
                acc2 += __shfl_down(acc2, o);
            }
            if (lane == 0) {
                s1f[row] = (float)acc1;
                s2g[row] = acc2;               // f64 ordering key
            }
        }
    }
}

// ---------------------------------------------------------------------------
// K2 (fused): 88 blocks = 11 sectors x 8 slices. Phase 1 is the proven
// slice top-16. Then last-arriving block per sector (device-scope atomic +
// __threadfence, rocPRIM last-block pattern) performs the merge (old K3)
// and writes the sector's output rows (old K4). Inactive rows are written
// by the c==0 blocks from the act values they already hold.
// ---------------------------------------------------------------------------
__global__ __launch_bounds__(NT) void fused_topk(
    const float* __restrict__ s1f, const double* __restrict__ s2g,
    const int* __restrict__ sec, const int* __restrict__ act,
    double* __restrict__ candV, int* __restrict__ candI,
    int* __restrict__ cnts, int* __restrict__ arrive,
    float* __restrict__ out)
{
    __shared__ double wV[4][TOPK];
    __shared__ int wI[4][TOPK];
    __shared__ int wCnt[4];
    __shared__ int sLast;
    __shared__ int sTopI[TOPK];
    __shared__ double sD[TOPK];
    __shared__ float sFidx[TOPK];
    __shared__ float sFill[TOPK];
    __shared__ int sM;

    int bx = blockIdx.x;
    int c = bx >> 3;       // sector 0..10
    int sl = bx & 7;       // slice 0..7
    int t = threadIdx.x;
    int lane = t & 63;
    int w = t >> 6;

    int j0 = sl * SLICE + 4 * t;
    int4 a4 = *(const int4*)(act + j0);
    int4 s4 = *(const int4*)(sec + j0);
    double2 d01 = *(const double2*)(s2g + j0);
    double2 d23 = *(const double2*)(s2g + j0 + 2);

    bool p0 = (a4.x != 0) && (s4.x == c);
    bool p1 = (a4.y != 0) && (s4.y == c);
    bool p2 = (a4.z != 0) && (s4.z == c);
    bool p3 = (a4.w != 0) && (s4.w == c);

    double v[4];
    int ix[4];
    v[0] = p0 ? d01.x : -INFINITY;  ix[0] = p0 ? (j0 + 0) : IDX_SENT;
    v[1] = p1 ? d01.y : -INFINITY;  ix[1] = p1 ? (j0 + 1) : IDX_SENT;
    v[2] = p2 ? d23.x : -INFINITY;  ix[2] = p2 ? (j0 + 2) : IDX_SENT;
    v[3] = p3 ? d23.y : -INFINITY;  ix[3] = p3 ? (j0 + 3) : IDX_SENT;

    int cnt = __popcll(__ballot(p0)) + __popcll(__ballot(p1)) +
              __popcll(__ballot(p2)) + __popcll(__ballot(p3));

    // inactive-row outputs: sector-independent, written once by c==0 blocks
    if (c == 0) {
        int av[4] = {a4.x, a4.y, a4.z, a4.w};
#pragma unroll
        for (int p = 0; p < 4; ++p) {
            if (av[p] == 0) {
                int rown = j0 + p;
                float4* o0 = (float4*)(out + (size_t)rown * TOPK);
                float4* o1 = (float4*)(out + (size_t)N * TOPK + (size_t)rown * TOPK);
                float4* o2 = (float4*)(out + 2 * (size_t)N * TOPK + (size_t)rown * TOPK);
                float4 z = make_float4(0.f, 0.f, 0.f, 0.f);
                o0[0] = z; o0[1] = z; o0[2] = z; o0[3] = z;
                o1[0] = make_float4(0.f, 1.f, 2.f, 3.f);
                o1[1] = make_float4(4.f, 5.f, 6.f, 7.f);
                o1[2] = make_float4(8.f, 9.f, 10.f, 11.f);
                o1[3] = make_float4(12.f, 13.f, 14.f, 15.f);
                o2[0] = z; o2[1] = z; o2[2] = z; o2[3] = z;
            }
        }
    }

    // ---- per-wave 16-round selection (proven) ----
    for (int r = 0; r < TOPK; ++r) {
        double bv = v[0];
        int bi = ix[0];
#pragma unroll
        for (int p = 1; p < 4; ++p)
            if (better(v[p], ix[p], bv, bi)) { bv = v[p]; bi = ix[p]; }
        for (int o = 32; o > 0; o >>= 1) {
            double ov = __shfl_xor(bv, o);
            int oi = __shfl_xor(bi, o);
            if (better(ov, oi, bv, bi)) { bv = ov; bi = oi; }
        }
#pragma unroll
        for (int p = 0; p < 4; ++p)
            if (ix[p] == bi) { v[p] = -INFINITY; ix[p] = IDX_SENT; }
        if (lane == 0) {
            wV[w][r] = bv;
            wI[w][r] = bi;
        }
    }
    if (lane == 0) wCnt[w] = cnt;
    __syncthreads();

    // ---- block merge (proven) + arrival ----
    if (w == 0) {
        double mv = wV[lane >> 4][lane & 15];
        int mi = wI[lane >> 4][lane & 15];
        for (int r = 0; r < TOPK; ++r) {
            double bv = mv;
            int bi = mi;
            for (int o = 32; o > 0; o >>= 1) {
                double ov = __shfl_xor(bv, o);
                int oi = __shfl_xor(bi, o);
                if (better(ov, oi, bv, bi)) { bv = ov; bi = oi; }
            }
            if (mi == bi) { mv = -INFINITY; mi = IDX_SENT; }
            if (lane == 0) {
                candV[bx * TOPK + r] = bv;
                candI[bx * TOPK + r] = bi;
            }
        }
        if (lane == 0) {
            cnts[bx] = wCnt[0] + wCnt[1] + wCnt[2] + wCnt[3];
            __threadfence();                       // release candV/candI/cnts
            int old = atomicAdd(&arrive[c], 1);    // device-scope
            sLast = (old == NSL - 1);
        }
    }
    __syncthreads();
    if (!sLast) return;

    // =========== merger path: this block is last of its sector ===========
    __threadfence();   // acquire: other slices' candV/candI/cnts

    if (w == 0) {
        // merge 8 sorted 16-lists (128 candidates, 2 per lane) — old K3
        const double* cbV = candV + (size_t)c * NSL * TOPK;
        const int* cbI = candI + (size_t)c * NSL * TOPK;
        double v0 = cbV[lane];
        int i0 = cbI[lane];
        double v1 = cbV[lane + 64];
        int i1 = cbI[lane + 64];
        for (int r = 0; r < TOPK; ++r) {
            double bv;
            int bi;
            if (better(v0, i0, v1, i1)) { bv = v0; bi = i0; }
            else                        { bv = v1; bi = i1; }
            for (int o = 32; o > 0; o >>= 1) {
                double ov = __shfl_xor(bv, o);
                int oi = __shfl_xor(bi, o);
                if (better(ov, oi, bv, bi)) { bv = ov; bi = oi; }
            }
            if (i0 == bi)      { v0 = -INFINITY; i0 = IDX_SENT; }
            else if (i1 == bi) { v1 = -INFINITY; i1 = IDX_SENT; }
            if (lane == 0) sTopI[r] = bi;
        }
        // m = min(16, total active in sector)
        int cl = (lane < NSL) ? cnts[c * NSL + lane] : 0;
        for (int o = 32; o > 0; o >>= 1) cl += __shfl_xor(cl, o);
        if (lane == 0) sM = (cl < TOPK) ? cl : TOPK;
    } else if (w == 1) {
        // fill indices: first 16 j failing the predicate — old K3 tail
        int cnt2 = 0;
        for (int basej = 0; basej < N && cnt2 < TOPK; basej += 64) {
            int j = basej + lane;
            bool fail = !((act[j] != 0) && (sec[j] == c));
            unsigned long long mask = __ballot(fail);
            if (fail) {
                int rank = cnt2 + __popcll(mask & ((1ull << lane) - 1));
                if (rank < TOPK) sFill[rank] = (float)j;
            }
            cnt2 += __popcll(mask);
        }
    }
    __syncthreads();

    // gather s2g of winners once into LDS
    if (t < TOPK) {
        int j = sTopI[t];
        sD[t] = (j == IDX_SENT) ? 0.0 : s2g[j];
        sFidx[t] = (j == IDX_SENT) ? 0.0f : (float)j;
    }
    __syncthreads();

    // ---- write this sector's active rows — old K4 ----
    int mm = sM;
    for (int i = t; i < N; i += NT) {
        if (act[i] != 0 && sec[i] == c) {
            double s1d = (double)s1f[i];
#pragma unroll
            for (int slot = 0; slot < TOPK; ++slot) {
                float wgt, fidx, fvalid;
                if (slot < mm) {
                    double x = s1d + sD[slot];
                    double attv = (x >= 0.0) ? x : NEG_SLOPE * x;
                    wgt = (float)attv;
                    fvalid = 1.0f;
                    fidx = sFidx[slot];
                } else {
                    wgt = 0.0f;
                    fvalid = 0.0f;
                    fidx = sFill[slot - mm];
                }
                out[(size_t)i * TOPK + slot] = wgt;
                out[(size_t)N * TOPK + (size_t)i * TOPK + slot] = fidx;
                out[2 * (size_t)N * TOPK + (size_t)i * TOPK + slot] = fvalid;
            }
        }
    }
}

extern "C" void kernel_launch(void* const* d_in, const int* in_sizes, int n_in,
                              void* d_out, int out_size, void* d_ws, size_t ws_size,
                              hipStream_t stream) {
    const float* E = (const float*)d_in[0];
    const float* W = (const float*)d_in[1];
    const float* a = (const float*)d_in[2];
    const int* sec = (const int*)d_in[3];
    const int* act = (const int*)d_in[4];  // bool input uploaded as int32

    // workspace (~116 KB, 8-byte aligned first)
    char* ws = (char*)d_ws;
    double* s2g = (double*)ws;                             // N f64
    double* candV = s2g + N;                               // NSEC*NSL*TOPK f64
    float* s1f = (float*)(candV + NSEC * NSL * TOPK);      // N f32
    int* candI = (int*)(s1f + N);                          // NSEC*NSL*TOPK i32
    int* cnts = candI + NSEC * NSL * TOPK;                 // NSEC*NSL
    int* arrive = cnts + NSEC * NSL;                       // NSEC arrival counters

    float* out = (float*)d_out;

    hipLaunchKernelGGL(compute_v_s, dim3(NB), dim3(NT), 0, stream,
                       E, W, a, s1f, s2g, arrive);
    hipLaunchKernelGGL(fused_topk, dim3(NSEC * NSL), dim3(NT), 0, stream,
                       s1f, s2g, sec, act, candV, candI, cnts, arrive, out);
}

// Round 2
// 113.444 us; speedup vs baseline: 1.6022x; 1.6022x over previous
//
#include <hip/hip_runtime.h>

#define N 8192
#define H 256
#define TOPK 16
#define NSEC 11
#define NEG_SLOPE 0.2
#define NB 256                 // K1 blocks (one per CU)
#define NT 256                 // threads per block
#define RPB (N / NB)           // 32 rows per block
#define NSL 8                  // slices per sector
#define SLICE (N / NSL)        // 1024 elements per slice
#define IDX_SENT 0x7fffffff

__device__ __forceinline__ bool better(double av, int ai, double bv, int bi) {
    return (av > bv) || (av == bv && ai < bi);
}

// ---------------------------------------------------------------------------
// K1: redundant v = W^T a per block (4 independent f64 chains, proven),
// then s1/s2 for the block's 32 rows. Block 0 zeroes the arrival counters
// for K2's last-block pattern (visible at the dispatch boundary).
// ---------------------------------------------------------------------------
__global__ __launch_bounds__(NT) void compute_v_s(
    const float* __restrict__ E, const float* __restrict__ W,
    const float* __restrict__ a,
    float* __restrict__ s1f, double* __restrict__ s2g,
    int* __restrict__ arrive)
{
    __shared__ float sa[2 * H];
    __shared__ double sv1[H];
    __shared__ double sv2[H];

    int t = threadIdx.x;
    int blk = blockIdx.x;
    int lane = t & 63;
    int w = t >> 6;  // wave 0..3

    if (blk == 0 && t < NSEC) arrive[t] = 0;

    sa[t] = a[t];
    sa[t + H] = a[t + H];
    __syncthreads();

    // ---- phase A: thread t owns column t; 4 independent chains ----
    {
        double a1_0 = 0.0, a1_1 = 0.0, a1_2 = 0.0, a1_3 = 0.0;
        double a2_0 = 0.0, a2_1 = 0.0, a2_2 = 0.0, a2_3 = 0.0;
        for (int j = 0; j < H; j += 4) {
            double w0 = (double)W[(j + 0) * H + t];
            double w1 = (double)W[(j + 1) * H + t];
            double w2 = (double)W[(j + 2) * H + t];
            double w3 = (double)W[(j + 3) * H + t];
            a1_0 += w0 * (double)sa[j + 0];
            a1_1 += w1 * (double)sa[j + 1];
            a1_2 += w2 * (double)sa[j + 2];
            a1_3 += w3 * (double)sa[j + 3];
            a2_0 += w0 * (double)sa[H + j + 0];
            a2_1 += w1 * (double)sa[H + j + 1];
            a2_2 += w2 * (double)sa[H + j + 2];
            a2_3 += w3 * (double)sa[H + j + 3];
        }
        sv1[t] = (a1_0 + a1_1) + (a1_2 + a1_3);
        sv2[t] = (a2_0 + a2_1) + (a2_2 + a2_3);
    }
    __syncthreads();

    // ---- phase B: rows [blk*32 .. +32), wave-per-row, loads batched ----
    {
        float4 e[RPB / 4];
#pragma unroll
        for (int q = 0; q < RPB / 4; ++q) {
            int row = blk * RPB + (w + 4 * q);
            e[q] = ((const float4*)(E + (size_t)row * H))[lane];
        }
        int base = lane * 4;
        double b10 = sv1[base + 0], b11 = sv1[base + 1],
               b12 = sv1[base + 2], b13 = sv1[base + 3];
        double b20 = sv2[base + 0], b21 = sv2[base + 1],
               b22 = sv2[base + 2], b23 = sv2[base + 3];
#pragma unroll
        for (int q = 0; q < RPB / 4; ++q) {
            int row = blk * RPB + (w + 4 * q);
            double acc1 = (double)e[q].x * b10 + (double)e[q].y * b11 +
                          (double)e[q].z * b12 + (double)e[q].w * b13;
            double acc2 = (double)e[q].x * b20 + (double)e[q].y * b21 +
                          (double)e[q].z * b22 + (double)e[q].w * b23;
            for (int o = 32; o > 0; o >>= 1) {
                acc1 += __shfl_down(acc1, o);
                acc2 += __shfl_down(acc2, o);
            }
            if (lane == 0) {
                s1f[row] = (float)acc1;
                s2g[row] = acc2;               // f64 ordering key
            }
        }
    }
}

// ---------------------------------------------------------------------------
// K2 (slice_merge): 88 blocks = 11 sectors x 8 slices. Proven slice top-16,
// then last-arriving block per sector performs ONLY the old-K3 work
// (merge 128 candidates -> top_idx, m, fill scan). The expensive row-write
// phase stays in the separate coalesced K3 below (round-1 lesson: doing the
// writes in 11 long-tail blocks cost ~110 us of latency-bound serial work).
// ---------------------------------------------------------------------------
__global__ __launch_bounds__(NT) void slice_merge(
    const double* __restrict__ s2g, const int* __restrict__ sec,
    const int* __restrict__ act,
    double* __restrict__ candV, int* __restrict__ candI,
    int* __restrict__ cnts, int* __restrict__ arrive,
    int* __restrict__ top_idx, int* __restrict__ fill_idx,
    int* __restrict__ m_arr)
{
    __shared__ double wV[4][TOPK];
    __shared__ int wI[4][TOPK];
    __shared__ int wCnt[4];
    __shared__ int sLast;

    int bx = blockIdx.x;
    int c = bx >> 3;       // sector 0..10
    int sl = bx & 7;       // slice 0..7
    int t = threadIdx.x;
    int lane = t & 63;
    int w = t >> 6;

    int j0 = sl * SLICE + 4 * t;
    int4 a4 = *(const int4*)(act + j0);
    int4 s4 = *(const int4*)(sec + j0);
    double2 d01 = *(const double2*)(s2g + j0);
    double2 d23 = *(const double2*)(s2g + j0 + 2);

    bool p0 = (a4.x != 0) && (s4.x == c);
    bool p1 = (a4.y != 0) && (s4.y == c);
    bool p2 = (a4.z != 0) && (s4.z == c);
    bool p3 = (a4.w != 0) && (s4.w == c);

    double v[4];
    int ix[4];
    v[0] = p0 ? d01.x : -INFINITY;  ix[0] = p0 ? (j0 + 0) : IDX_SENT;
    v[1] = p1 ? d01.y : -INFINITY;  ix[1] = p1 ? (j0 + 1) : IDX_SENT;
    v[2] = p2 ? d23.x : -INFINITY;  ix[2] = p2 ? (j0 + 2) : IDX_SENT;
    v[3] = p3 ? d23.y : -INFINITY;  ix[3] = p3 ? (j0 + 3) : IDX_SENT;

    int cnt = __popcll(__ballot(p0)) + __popcll(__ballot(p1)) +
              __popcll(__ballot(p2)) + __popcll(__ballot(p3));

    // ---- per-wave 16-round selection (proven) ----
    for (int r = 0; r < TOPK; ++r) {
        double bv = v[0];
        int bi = ix[0];
#pragma unroll
        for (int p = 1; p < 4; ++p)
            if (better(v[p], ix[p], bv, bi)) { bv = v[p]; bi = ix[p]; }
        for (int o = 32; o > 0; o >>= 1) {
            double ov = __shfl_xor(bv, o);
            int oi = __shfl_xor(bi, o);
            if (better(ov, oi, bv, bi)) { bv = ov; bi = oi; }
        }
#pragma unroll
        for (int p = 0; p < 4; ++p)
            if (ix[p] == bi) { v[p] = -INFINITY; ix[p] = IDX_SENT; }
        if (lane == 0) {
            wV[w][r] = bv;
            wI[w][r] = bi;
        }
    }
    if (lane == 0) wCnt[w] = cnt;
    __syncthreads();

    // ---- block merge (proven) + arrival ----
    if (w == 0) {
        double mv = wV[lane >> 4][lane & 15];
        int mi = wI[lane >> 4][lane & 15];
        for (int r = 0; r < TOPK; ++r) {
            double bv = mv;
            int bi = mi;
            for (int o = 32; o > 0; o >>= 1) {
                double ov = __shfl_xor(bv, o);
                int oi = __shfl_xor(bi, o);
                if (better(ov, oi, bv, bi)) { bv = ov; bi = oi; }
            }
            if (mi == bi) { mv = -INFINITY; mi = IDX_SENT; }
            if (lane == 0) {
                candV[bx * TOPK + r] = bv;
                candI[bx * TOPK + r] = bi;
            }
        }
        if (lane == 0) {
            cnts[bx] = wCnt[0] + wCnt[1] + wCnt[2] + wCnt[3];
            __threadfence();                       // release candV/candI/cnts
            int old = atomicAdd(&arrive[c], 1);    // device-scope
            sLast = (old == NSL - 1);
        }
    }
    __syncthreads();
    if (!sLast) return;

    // ========= merger tail (old K3 only — cheap, ~2 us) =========
    __threadfence();   // acquire: other slices' candV/candI/cnts

    if (w == 0) {
        // merge 8 sorted 16-lists (128 candidates, 2 per lane)
        const double* cbV = candV + (size_t)c * NSL * TOPK;
        const int* cbI = candI + (size_t)c * NSL * TOPK;
        double v0 = cbV[lane];
        int i0 = cbI[lane];
        double v1 = cbV[lane + 64];
        int i1 = cbI[lane + 64];
        for (int r = 0; r < TOPK; ++r) {
            double bv;
            int bi;
            if (better(v0, i0, v1, i1)) { bv = v0; bi = i0; }
            else                        { bv = v1; bi = i1; }
            for (int o = 32; o > 0; o >>= 1) {
                double ov = __shfl_xor(bv, o);
                int oi = __shfl_xor(bi, o);
                if (better(ov, oi, bv, bi)) { bv = ov; bi = oi; }
            }
            if (i0 == bi)      { v0 = -INFINITY; i0 = IDX_SENT; }
            else if (i1 == bi) { v1 = -INFINITY; i1 = IDX_SENT; }
            if (lane == 0) top_idx[c * TOPK + r] = (bi == IDX_SENT) ? -1 : bi;
        }
        // m = min(16, total active in sector)
        int cl = (lane < NSL) ? cnts[c * NSL + lane] : 0;
        for (int o = 32; o > 0; o >>= 1) cl += __shfl_xor(cl, o);
        if (lane == 0) m_arr[c] = (cl < TOPK) ? cl : TOPK;
    } else if (w == 1) {
        // fill indices: first 16 j failing the predicate (usually 1 iter)
        int cnt2 = 0;
        for (int basej = 0; basej < N && cnt2 < TOPK; basej += 64) {
            int j = basej + lane;
            bool fail = !((act[j] != 0) && (sec[j] == c));
            unsigned long long mask = __ballot(fail);
            if (fail) {
                int rank = cnt2 + __popcll(mask & ((1ull << lane) - 1));
                if (rank < TOPK) fill_idx[c * TOPK + rank] = j;
            }
            cnt2 += __popcll(mask);
        }
    }
}

// ---------------------------------------------------------------------------
// K3: write outputs (weight, index-as-float, valid-as-float planes).
// Round-0 proven coalesced writer, unchanged.
// ---------------------------------------------------------------------------
__global__ __launch_bounds__(NT) void write_out(const float* __restrict__ s1f,
                                                const double* __restrict__ s2g,
                                                const int* __restrict__ sec,
                                                const int* __restrict__ act,
                                                const int* __restrict__ top_idx,
                                                const int* __restrict__ fill_idx,
                                                const int* __restrict__ m_arr,
                                                float* __restrict__ out) {
    int gid = blockIdx.x * NT + threadIdx.x;  // N*TOPK total
    int i = gid >> 4;
    int slot = gid & 15;

    float wgt = 0.0f;
    float fidx;
    float fvalid = 0.0f;

    if (act[i] == 0) {
        fidx = (float)slot;  // all -inf row: stable top_k -> indices 0..15
    } else {
        int c = sec[i];
        int m = m_arr[c];
        if (slot < m) {
            int j = top_idx[c * TOPK + slot];
            double x = (double)s1f[i] + s2g[j];
            double attv = (x >= 0.0) ? x : NEG_SLOPE * x;
            wgt = (float)attv;
            fvalid = 1.0f;
            fidx = (float)j;
        } else {
            fidx = (float)fill_idx[c * TOPK + (slot - m)];
        }
    }

    out[gid] = wgt;
    out[N * TOPK + gid] = fidx;
    out[2 * N * TOPK + gid] = fvalid;
}

extern "C" void kernel_launch(void* const* d_in, const int* in_sizes, int n_in,
                              void* d_out, int out_size, void* d_ws, size_t ws_size,
                              hipStream_t stream) {
    const float* E = (const float*)d_in[0];
    const float* W = (const float*)d_in[1];
    const float* a = (const float*)d_in[2];
    const int* sec = (const int*)d_in[3];
    const int* act = (const int*)d_in[4];  // bool input uploaded as int32

    // workspace (~116 KB, 8-byte aligned first)
    char* ws = (char*)d_ws;
    double* s2g = (double*)ws;                             // N f64
    double* candV = s2g + N;                               // NSEC*NSL*TOPK f64
    float* s1f = (float*)(candV + NSEC * NSL * TOPK);      // N f32
    int* candI = (int*)(s1f + N);                          // NSEC*NSL*TOPK i32
    int* cnts = candI + NSEC * NSL * TOPK;                 // NSEC*NSL = 88
    int* top_idx = cnts + NSEC * NSL;                      // NSEC*TOPK
    int* fill_idx = top_idx + NSEC * TOPK;                 // NSEC*TOPK
    int* m_arr = fill_idx + NSEC * TOPK;                   // NSEC
    int* arrive = m_arr + NSEC;                            // NSEC arrival counters

    float* out = (float*)d_out;

    hipLaunchKernelGGL(compute_v_s, dim3(NB), dim3(NT), 0, stream,
                       E, W, a, s1f, s2g, arrive);
    hipLaunchKernelGGL(slice_merge, dim3(NSEC * NSL), dim3(NT), 0, stream,
                       s2g, sec, act, candV, candI, cnts, arrive,
                       top_idx, fill_idx, m_arr);
    hipLaunchKernelGGL(write_out, dim3((N * TOPK) / NT), dim3(NT), 0, stream,
                       s1f, s2g, sec, act, top_idx, fill_idx, m_arr, out);
}